// Round 1
// baseline (2627.324 us; speedup 1.0000x reference)
//
#include <hip/hip_runtime.h>
#include <cstdint>

#define NN 100000
#define NE 400000
#define NG 2048
#define H  32
#define ED 16

// ---------------- lin0: feat = relu(x @ W0^T + b0) ----------------
__global__ __launch_bounds__(256) void k_lin0(const float* __restrict__ x,
                                              const float* __restrict__ W0,
                                              const float* __restrict__ b0,
                                              float* __restrict__ feat) {
  int id = blockIdx.x * 256 + threadIdx.x;     // N*32 threads exactly
  int n = id >> 5, o = id & 31;
  const float* xr = x + n * H;
  const float* wr = W0 + o * H;
  float acc = b0[o];
#pragma unroll
  for (int i = 0; i < H; ++i) acc = fmaf(xr[i], wr[i], acc);
  feat[id] = fmaxf(acc, 0.f);
}

// ---- per-iteration: agg init (root term + bconv) and nodeb = feat @ be-matrix ----
__global__ __launch_bounds__(256) void k_pre(const float* __restrict__ feat,
                                             const float* __restrict__ Wroot,
                                             const float* __restrict__ bconv,
                                             const float* __restrict__ be,
                                             float* __restrict__ agg,
                                             float* __restrict__ nodeb) {
  int id = blockIdx.x * 256 + threadIdx.x;     // N*32
  int n = id >> 5, o = id & 31;
  const float* fr = feat + n * H;
  float a = bconv[o];
  float nb = 0.f;
#pragma unroll
  for (int i = 0; i < H; ++i) {
    float f = fr[i];
    a  = fmaf(f, Wroot[o * H + i], a);
    nb = fmaf(f, be[i * H + o], nb);
  }
  agg[id]   = a;
  nodeb[id] = nb;
}

// ---- g[n, j] = sum_i feat[n,i] * We_flat[i*512 + j]  (feat @ We as 32x512) ----
__global__ __launch_bounds__(256) void k_g(const float* __restrict__ feat,
                                           const float* __restrict__ We,
                                           float* __restrict__ g) {
  int id = blockIdx.x * 256 + threadIdx.x;     // N*512 threads exactly
  int n = id >> 9, j = id & 511;
  const float* fr = feat + n * H;
  float acc = 0.f;
#pragma unroll
  for (int i = 0; i < H; ++i) acc = fmaf(fr[i], We[i * 512 + j], acc);
  g[id] = acc;
}

// ---- edge phase using g: msg[e,o] = sum_k ea[e,k]*g[src,o*16+k] + nodeb[src,o] ----
__global__ __launch_bounds__(256) void k_edge(const int* __restrict__ ei,
                                              const float* __restrict__ ea,
                                              const float* __restrict__ g,
                                              const float* __restrict__ nodeb,
                                              float* __restrict__ agg) {
  int id = blockIdx.x * 256 + threadIdx.x;     // E*32 threads exactly
  int e = id >> 5, o = id & 31;
  int src = ei[e];
  int dst = ei[NE + e];
  const float4* g4 = (const float4*)(g + (size_t)src * 512 + o * 16);
  const float4* e4 = (const float4*)(ea + (size_t)e * ED);
  float acc = nodeb[src * H + o];
#pragma unroll
  for (int q = 0; q < 4; ++q) {
    float4 gv = g4[q];
    float4 ev = e4[q];
    acc = fmaf(ev.x, gv.x, acc);
    acc = fmaf(ev.y, gv.y, acc);
    acc = fmaf(ev.z, gv.z, acc);
    acc = fmaf(ev.w, gv.w, acc);
  }
  unsafeAtomicAdd(&agg[dst * H + o], acc);
}

// ---- fallback edge phase (no g buffer): direct per-edge contraction ----
__global__ __launch_bounds__(256) void k_edge_direct(const int* __restrict__ ei,
                                                     const float* __restrict__ ea,
                                                     const float* __restrict__ feat,
                                                     const float* __restrict__ We,
                                                     const float* __restrict__ nodeb,
                                                     float* __restrict__ agg) {
  int id = blockIdx.x * 256 + threadIdx.x;
  int e = id >> 5, o = id & 31;
  int src = ei[e];
  int dst = ei[NE + e];
  float fo = feat[src * H + o];
  const float* ear = ea + (size_t)e * ED;
  float ek[ED];
#pragma unroll
  for (int k = 0; k < ED; ++k) ek[k] = ear[k];
  float acc = nodeb[src * H + o];
#pragma unroll
  for (int i = 0; i < H; ++i) {
    float fi = __shfl(fo, i, 32);
    const float* wr = We + i * 512 + o * 16;
    float t = 0.f;
#pragma unroll
    for (int k = 0; k < ED; ++k) t = fmaf(ek[k], wr[k], t);
    acc = fmaf(fi, t, acc);
  }
  unsafeAtomicAdd(&agg[dst * H + o], acc);
}

// ---- GRU cell, fused per node; writes new h into feat ----
__global__ __launch_bounds__(256) void k_gru(const float* __restrict__ agg,
                                             const float* __restrict__ Wih,
                                             const float* __restrict__ bih,
                                             const float* __restrict__ Whh,
                                             const float* __restrict__ bhh,
                                             float* __restrict__ feat) {
  __shared__ float sm[8][H];
  __shared__ float sh[8][H];
  int id = blockIdx.x * 256 + threadIdx.x;     // N*32
  int o = id & 31;
  int ln = threadIdx.x >> 5;
  float m = fmaxf(agg[id], 0.f);               // relu(conv)
  float h = feat[id];
  sm[ln][o] = m;
  sh[ln][o] = h;
  __syncthreads();
  float gir = bih[o], giz = bih[H + o], gin = bih[2 * H + o];
  float ghr = bhh[o], ghz = bhh[H + o], ghn = bhh[2 * H + o];
#pragma unroll
  for (int i = 0; i < H; ++i) {
    float mi = sm[ln][i], hi = sh[ln][i];
    gir = fmaf(mi, Wih[o * H + i], gir);
    giz = fmaf(mi, Wih[(H + o) * H + i], giz);
    gin = fmaf(mi, Wih[(2 * H + o) * H + i], gin);
    ghr = fmaf(hi, Whh[o * H + i], ghr);
    ghz = fmaf(hi, Whh[(H + o) * H + i], ghz);
    ghn = fmaf(hi, Whh[(2 * H + o) * H + i], ghn);
  }
  float r = 1.f / (1.f + expf(-(gir + ghr)));
  float z = 1.f / (1.f + expf(-(giz + ghz)));
  float nn = tanhf(fmaf(r, ghn, gin));
  feat[id] = (1.f - z) * nn + z * h;
}

// ---- global mean pool (sums + counts via atomics) ----
__global__ __launch_bounds__(256) void k_pool(const float* __restrict__ feat,
                                              const int* __restrict__ batch,
                                              float* __restrict__ pooled,
                                              float* __restrict__ cnts) {
  int id = blockIdx.x * 256 + threadIdx.x;     // N*32
  int n = id >> 5, o = id & 31;
  int b = batch[n];
  unsafeAtomicAdd(&pooled[b * H + o], feat[id]);
  if (o == 0) unsafeAtomicAdd(&cnts[b], 1.f);
}

// ---- final head: y[g] = (pooled[g]/cnt) . W1 + b1 ----
__global__ __launch_bounds__(256) void k_final(const float* __restrict__ pooled,
                                               const float* __restrict__ cnts,
                                               const float* __restrict__ W1,
                                               const float* __restrict__ b1,
                                               float* __restrict__ y) {
  int gph = blockIdx.x * 256 + threadIdx.x;
  if (gph >= NG) return;
  float c = fmaxf(cnts[gph], 1.f);
  float acc = 0.f;
#pragma unroll
  for (int o = 0; o < H; ++o) acc = fmaf(pooled[gph * H + o], W1[o], acc);
  y[gph] = acc / c + b1[0];
}

extern "C" void kernel_launch(void* const* d_in, const int* in_sizes, int n_in,
                              void* d_out, int out_size, void* d_ws, size_t ws_size,
                              hipStream_t stream) {
  const float* x     = (const float*)d_in[0];
  const int*   ei    = (const int*)d_in[1];
  const float* ea    = (const float*)d_in[2];
  const int*   batch = (const int*)d_in[3];
  const float* W0    = (const float*)d_in[4];
  const float* b0    = (const float*)d_in[5];
  const float* We    = (const float*)d_in[6];
  const float* be    = (const float*)d_in[7];
  const float* Wroot = (const float*)d_in[8];
  const float* bconv = (const float*)d_in[9];
  const float* Wih   = (const float*)d_in[10];
  const float* bih   = (const float*)d_in[11];
  const float* Whh   = (const float*)d_in[12];
  const float* bhh   = (const float*)d_in[13];
  const float* W1    = (const float*)d_in[14];
  const float* b1    = (const float*)d_in[15];

  float* ws     = (float*)d_ws;
  float* feat   = ws;                       // N*32
  float* agg    = ws + 3200000;             // N*32
  float* nodeb  = ws + 6400000;             // N*32
  float* pooled = ws + 9600000;             // G*32
  float* cnts   = ws + 9665536;             // G
  float* g      = ws + 9667584;             // N*512 (204.8 MB)
  const size_t need_g = (size_t)(9667584 + 51200000) * 4;
  bool use_g = ws_size >= need_g;

  const int NB_NODE = (NN * H) / 256;       // 12500, exact
  const int NB_EDGE = (NE * H) / 256;       // 50000, exact
  const int NB_G    = (NN * 512) / 256;     // 200000, exact

  k_lin0<<<NB_NODE, 256, 0, stream>>>(x, W0, b0, feat);
  for (int it = 0; it < 3; ++it) {
    k_pre<<<NB_NODE, 256, 0, stream>>>(feat, Wroot, bconv, be, agg, nodeb);
    if (use_g) {
      k_g<<<NB_G, 256, 0, stream>>>(feat, We, g);
      k_edge<<<NB_EDGE, 256, 0, stream>>>(ei, ea, g, nodeb, agg);
    } else {
      k_edge_direct<<<NB_EDGE, 256, 0, stream>>>(ei, ea, feat, We, nodeb, agg);
    }
    k_gru<<<NB_NODE, 256, 0, stream>>>(agg, Wih, bih, Whh, bhh, feat);
  }
  hipMemsetAsync(pooled, 0, (size_t)(NG * H + NG) * 4, stream);
  k_pool<<<NB_NODE, 256, 0, stream>>>(feat, batch, pooled, cnts);
  k_final<<<(NG + 255) / 256, 256, 0, stream>>>(pooled, cnts, W1, b1, (float*)d_out);
}

// Round 2
// 1685.755 us; speedup vs baseline: 1.5585x; 1.5585x over previous
//
#include <hip/hip_runtime.h>
#include <cstdint>

#define NN 100000
#define NE 400000
#define NG 2048
#define H  32
#define ED 16
#define NPB 20   // nodes per block in k_g (100000 % 20 == 0)

// ---------------- lin0: feat = relu(x @ W0^T + b0) ----------------
__global__ __launch_bounds__(256) void k_lin0(const float* __restrict__ x,
                                              const float* __restrict__ W0,
                                              const float* __restrict__ b0,
                                              float* __restrict__ feat) {
  int id = blockIdx.x * 256 + threadIdx.x;     // N*32 threads exactly
  int n = id >> 5, o = id & 31;
  const float* xr = x + n * H;
  const float* wr = W0 + o * H;
  float acc = b0[o];
#pragma unroll
  for (int i = 0; i < H; ++i) acc = fmaf(xr[i], wr[i], acc);
  feat[id] = fmaxf(acc, 0.f);
}

// ---- per-iteration: agg init (root term + bconv) and nodeb = feat @ be-matrix ----
__global__ __launch_bounds__(256) void k_pre(const float* __restrict__ feat,
                                             const float* __restrict__ Wroot,
                                             const float* __restrict__ bconv,
                                             const float* __restrict__ be,
                                             float* __restrict__ agg,
                                             float* __restrict__ nodeb) {
  int id = blockIdx.x * 256 + threadIdx.x;     // N*32
  int n = id >> 5, o = id & 31;
  const float* fr = feat + n * H;
  float a = bconv[o];
  float nb = 0.f;
#pragma unroll
  for (int i = 0; i < H; ++i) {
    float f = fr[i];
    a  = fmaf(f, Wroot[o * H + i], a);
    nb = fmaf(f, be[i * H + o], nb);
  }
  agg[id]   = a;
  nodeb[id] = nb;
}

// ---- g[n, j] = sum_i feat[n,i] * We_flat[i*512 + j] ----
// Register-blocked: each thread holds one float4 column of We (32 x float4),
// block stages NPB feat rows in LDS, thread emits one float4 per node.
__global__ __launch_bounds__(256) void k_g(const float* __restrict__ feat,
                                           const float* __restrict__ We,
                                           float* __restrict__ g) {
  __shared__ float sf[NPB * H];
  int t = threadIdx.x;
  int base = blockIdx.x * NPB;                 // grid = NN/NPB blocks
  for (int idx = t; idx < NPB * H; idx += 256)
    sf[idx] = feat[base * H + idx];

  int cj = t & 127;                            // float4 column 0..127
  int half = t >> 7;                           // 0..1 : which node parity
  const float4* We4 = (const float4*)We;       // [32][128] float4
  float4 wcol[H];
#pragma unroll
  for (int i = 0; i < H; ++i) wcol[i] = We4[i * 128 + cj];
  __syncthreads();

  float4* g4 = (float4*)g;
  for (int k = 0; k < NPB / 2; ++k) {
    int ln = 2 * k + half;                     // local node
    float4 acc = {0.f, 0.f, 0.f, 0.f};
#pragma unroll
    for (int i = 0; i < H; ++i) {
      float fi = sf[ln * H + i];
      acc.x = fmaf(fi, wcol[i].x, acc.x);
      acc.y = fmaf(fi, wcol[i].y, acc.y);
      acc.z = fmaf(fi, wcol[i].z, acc.z);
      acc.w = fmaf(fi, wcol[i].w, acc.w);
    }
    g4[(size_t)(base + ln) * 128 + cj] = acc;
  }
}

// ---- edge phase using g: msg[e,o] = sum_k ea[e,k]*g[src,o*16+k] + nodeb[src,o] ----
__global__ __launch_bounds__(256) void k_edge(const int* __restrict__ ei,
                                              const float* __restrict__ ea,
                                              const float* __restrict__ g,
                                              const float* __restrict__ nodeb,
                                              float* __restrict__ agg) {
  int id = blockIdx.x * 256 + threadIdx.x;     // E*32 threads exactly
  int e = id >> 5, o = id & 31;
  int src = ei[e];
  int dst = ei[NE + e];
  const float4* g4 = (const float4*)(g + (size_t)src * 512 + o * 16);
  const float4* e4 = (const float4*)(ea + (size_t)e * ED);
  float acc = nodeb[src * H + o];
#pragma unroll
  for (int q = 0; q < 4; ++q) {
    float4 gv = g4[q];
    float4 ev = e4[q];
    acc = fmaf(ev.x, gv.x, acc);
    acc = fmaf(ev.y, gv.y, acc);
    acc = fmaf(ev.z, gv.z, acc);
    acc = fmaf(ev.w, gv.w, acc);
  }
  unsafeAtomicAdd(&agg[dst * H + o], acc);
}

// ---- fallback edge phase (no g buffer): direct per-edge contraction ----
__global__ __launch_bounds__(256) void k_edge_direct(const int* __restrict__ ei,
                                                     const float* __restrict__ ea,
                                                     const float* __restrict__ feat,
                                                     const float* __restrict__ We,
                                                     const float* __restrict__ nodeb,
                                                     float* __restrict__ agg) {
  int id = blockIdx.x * 256 + threadIdx.x;
  int e = id >> 5, o = id & 31;
  int src = ei[e];
  int dst = ei[NE + e];
  float fo = feat[src * H + o];
  const float* ear = ea + (size_t)e * ED;
  float ek[ED];
#pragma unroll
  for (int k = 0; k < ED; ++k) ek[k] = ear[k];
  float acc = nodeb[src * H + o];
#pragma unroll
  for (int i = 0; i < H; ++i) {
    float fi = __shfl(fo, i, 32);
    const float* wr = We + i * 512 + o * 16;
    float t = 0.f;
#pragma unroll
    for (int k = 0; k < ED; ++k) t = fmaf(ek[k], wr[k], t);
    acc = fmaf(fi, t, acc);
  }
  unsafeAtomicAdd(&agg[dst * H + o], acc);
}

// ---- GRU cell, fused per node; writes new h into feat ----
__global__ __launch_bounds__(256) void k_gru(const float* __restrict__ agg,
                                             const float* __restrict__ Wih,
                                             const float* __restrict__ bih,
                                             const float* __restrict__ Whh,
                                             const float* __restrict__ bhh,
                                             float* __restrict__ feat) {
  __shared__ float sm[8][H];
  __shared__ float sh[8][H];
  int id = blockIdx.x * 256 + threadIdx.x;     // N*32
  int o = id & 31;
  int ln = threadIdx.x >> 5;
  float m = fmaxf(agg[id], 0.f);               // relu(conv)
  float h = feat[id];
  sm[ln][o] = m;
  sh[ln][o] = h;
  __syncthreads();
  float gir = bih[o], giz = bih[H + o], gin = bih[2 * H + o];
  float ghr = bhh[o], ghz = bhh[H + o], ghn = bhh[2 * H + o];
#pragma unroll
  for (int i = 0; i < H; ++i) {
    float mi = sm[ln][i], hi = sh[ln][i];
    gir = fmaf(mi, Wih[o * H + i], gir);
    giz = fmaf(mi, Wih[(H + o) * H + i], giz);
    gin = fmaf(mi, Wih[(2 * H + o) * H + i], gin);
    ghr = fmaf(hi, Whh[o * H + i], ghr);
    ghz = fmaf(hi, Whh[(H + o) * H + i], ghz);
    ghn = fmaf(hi, Whh[(2 * H + o) * H + i], ghn);
  }
  float r = 1.f / (1.f + expf(-(gir + ghr)));
  float z = 1.f / (1.f + expf(-(giz + ghz)));
  float nn = tanhf(fmaf(r, ghn, gin));
  feat[id] = (1.f - z) * nn + z * h;
}

// ---- global mean pool (sums + counts via atomics) ----
__global__ __launch_bounds__(256) void k_pool(const float* __restrict__ feat,
                                              const int* __restrict__ batch,
                                              float* __restrict__ pooled,
                                              float* __restrict__ cnts) {
  int id = blockIdx.x * 256 + threadIdx.x;     // N*32
  int n = id >> 5, o = id & 31;
  int b = batch[n];
  unsafeAtomicAdd(&pooled[b * H + o], feat[id]);
  if (o == 0) unsafeAtomicAdd(&cnts[b], 1.f);
}

// ---- final head: y[g] = (pooled[g]/cnt) . W1 + b1 ----
__global__ __launch_bounds__(256) void k_final(const float* __restrict__ pooled,
                                               const float* __restrict__ cnts,
                                               const float* __restrict__ W1,
                                               const float* __restrict__ b1,
                                               float* __restrict__ y) {
  int gph = blockIdx.x * 256 + threadIdx.x;
  if (gph >= NG) return;
  float c = fmaxf(cnts[gph], 1.f);
  float acc = 0.f;
#pragma unroll
  for (int o = 0; o < H; ++o) acc = fmaf(pooled[gph * H + o], W1[o], acc);
  y[gph] = acc / c + b1[0];
}

extern "C" void kernel_launch(void* const* d_in, const int* in_sizes, int n_in,
                              void* d_out, int out_size, void* d_ws, size_t ws_size,
                              hipStream_t stream) {
  const float* x     = (const float*)d_in[0];
  const int*   ei    = (const int*)d_in[1];
  const float* ea    = (const float*)d_in[2];
  const int*   batch = (const int*)d_in[3];
  const float* W0    = (const float*)d_in[4];
  const float* b0    = (const float*)d_in[5];
  const float* We    = (const float*)d_in[6];
  const float* be    = (const float*)d_in[7];
  const float* Wroot = (const float*)d_in[8];
  const float* bconv = (const float*)d_in[9];
  const float* Wih   = (const float*)d_in[10];
  const float* bih   = (const float*)d_in[11];
  const float* Whh   = (const float*)d_in[12];
  const float* bhh   = (const float*)d_in[13];
  const float* W1    = (const float*)d_in[14];
  const float* b1    = (const float*)d_in[15];

  float* ws     = (float*)d_ws;
  float* feat   = ws;                       // N*32
  float* agg    = ws + 3200000;             // N*32
  float* nodeb  = ws + 6400000;             // N*32
  float* pooled = ws + 9600000;             // G*32
  float* cnts   = ws + 9665536;             // G
  float* g      = ws + 9667584;             // N*512 (204.8 MB)
  const size_t need_g = (size_t)(9667584 + 51200000) * 4;
  bool use_g = ws_size >= need_g;

  const int NB_NODE = (NN * H) / 256;       // 12500, exact
  const int NB_EDGE = (NE * H) / 256;       // 50000, exact

  k_lin0<<<NB_NODE, 256, 0, stream>>>(x, W0, b0, feat);
  for (int it = 0; it < 3; ++it) {
    k_pre<<<NB_NODE, 256, 0, stream>>>(feat, Wroot, bconv, be, agg, nodeb);
    if (use_g) {
      k_g<<<NN / NPB, 256, 0, stream>>>(feat, We, g);
      k_edge<<<NB_EDGE, 256, 0, stream>>>(ei, ea, g, nodeb, agg);
    } else {
      k_edge_direct<<<NB_EDGE, 256, 0, stream>>>(ei, ea, feat, We, nodeb, agg);
    }
    k_gru<<<NB_NODE, 256, 0, stream>>>(agg, Wih, bih, Whh, bhh, feat);
  }
  hipMemsetAsync(pooled, 0, (size_t)(NG * H + NG) * 4, stream);
  k_pool<<<NB_NODE, 256, 0, stream>>>(feat, batch, pooled, cnts);
  k_final<<<(NG + 255) / 256, 256, 0, stream>>>(pooled, cnts, W1, b1, (float*)d_out);
}

// Round 3
// 894.359 us; speedup vs baseline: 2.9377x; 1.8849x over previous
//
#include <hip/hip_runtime.h>
#include <cstdint>

#define NN 100000
#define NE 400000
#define NG 2048
#define H  32
#define ED 16
#define NPB 20    // nodes per block in k_g
#define GNPB 20   // nodes per group in k_gru2 (NN % 20 == 0)
#define SMP 36    // padded row stride (floats) for sm/sh in k_gru2

// ---------------- lin0: feat = relu(x @ W0^T + b0) ----------------
__global__ __launch_bounds__(256) void k_lin0(const float* __restrict__ x,
                                              const float* __restrict__ W0,
                                              const float* __restrict__ b0,
                                              float* __restrict__ feat) {
  __shared__ float w0t[1024];                  // W0^T[i][o]
  int t = threadIdx.x;
  for (int idx = t; idx < 1024; idx += 256) {
    int o = idx >> 5, i = idx & 31;
    w0t[(i << 5) | o] = W0[idx];
  }
  __syncthreads();
  int id = blockIdx.x * 256 + t;               // N*32 threads exactly
  int n = id >> 5, o = id & 31;
  const float* xr = x + n * H;
  float acc = b0[o];
#pragma unroll
  for (int i = 0; i < H; ++i) acc = fmaf(xr[i], w0t[(i << 5) | o], acc);
  feat[id] = fmaxf(acc, 0.f);
}

// ---- per-iteration: agg init (root term + bconv) and nodeb = feat @ be-matrix ----
__global__ __launch_bounds__(256) void k_pre(const float* __restrict__ feat,
                                             const float* __restrict__ Wroot,
                                             const float* __restrict__ bconv,
                                             const float* __restrict__ be,
                                             float* __restrict__ agg,
                                             float* __restrict__ nodeb) {
  __shared__ float wrt[1024];                  // Wroot^T[i][o]
  int t = threadIdx.x;
  for (int idx = t; idx < 1024; idx += 256) {
    int o = idx >> 5, i = idx & 31;
    wrt[(i << 5) | o] = Wroot[idx];
  }
  __syncthreads();
  int id = blockIdx.x * 256 + t;               // N*32
  int n = id >> 5, o = id & 31;
  const float* fr = feat + n * H;
  float a = bconv[o];
  float nb = 0.f;
#pragma unroll
  for (int i = 0; i < H; ++i) {
    float f = fr[i];
    a  = fmaf(f, wrt[(i << 5) | o], a);
    nb = fmaf(f, be[(i << 5) | o], nb);        // be is lane-coalesced already
  }
  agg[id]   = a;
  nodeb[id] = nb;
}

// ---- g[n, j] = sum_i feat[n,i] * We_flat[i*512 + j] ----
__global__ __launch_bounds__(256) void k_g(const float* __restrict__ feat,
                                           const float* __restrict__ We,
                                           float* __restrict__ g) {
  __shared__ float sf[NPB * H];
  int t = threadIdx.x;
  int base = blockIdx.x * NPB;                 // grid = NN/NPB blocks
  for (int idx = t; idx < NPB * H; idx += 256)
    sf[idx] = feat[base * H + idx];

  int cj = t & 127;                            // float4 column 0..127
  int half = t >> 7;                           // node parity
  const float4* We4 = (const float4*)We;       // [32][128] float4
  float4 wcol[H];
#pragma unroll
  for (int i = 0; i < H; ++i) wcol[i] = We4[i * 128 + cj];
  __syncthreads();

  float4* g4 = (float4*)g;
  for (int k = 0; k < NPB / 2; ++k) {
    int ln = 2 * k + half;
    float4 acc = {0.f, 0.f, 0.f, 0.f};
#pragma unroll
    for (int i = 0; i < H; ++i) {
      float fi = sf[ln * H + i];
      acc.x = fmaf(fi, wcol[i].x, acc.x);
      acc.y = fmaf(fi, wcol[i].y, acc.y);
      acc.z = fmaf(fi, wcol[i].z, acc.z);
      acc.w = fmaf(fi, wcol[i].w, acc.w);
    }
    g4[(size_t)(base + ln) * 128 + cj] = acc;
  }
}

// ---- edge phase: msg[e,o] = sum_k ea[e,k]*g[src,o*16+k] + nodeb[src,o] ----
__global__ __launch_bounds__(256) void k_edge(const int* __restrict__ ei,
                                              const float* __restrict__ ea,
                                              const float* __restrict__ g,
                                              const float* __restrict__ nodeb,
                                              float* __restrict__ agg) {
  int id = blockIdx.x * 256 + threadIdx.x;     // E*32 threads exactly
  int e = id >> 5, o = id & 31;
  int src = ei[e];
  int dst = ei[NE + e];
  const float4* g4 = (const float4*)(g + (size_t)src * 512 + o * 16);
  const float4* e4 = (const float4*)(ea + (size_t)e * ED);
  float acc = nodeb[src * H + o];
#pragma unroll
  for (int q = 0; q < 4; ++q) {
    float4 gv = g4[q];
    float4 ev = e4[q];
    acc = fmaf(ev.x, gv.x, acc);
    acc = fmaf(ev.y, gv.y, acc);
    acc = fmaf(ev.z, gv.z, acc);
    acc = fmaf(ev.w, gv.w, acc);
  }
  unsafeAtomicAdd(&agg[dst * H + o], acc);
}

// ---- fallback edge phase (no g buffer) ----
__global__ __launch_bounds__(256) void k_edge_direct(const int* __restrict__ ei,
                                                     const float* __restrict__ ea,
                                                     const float* __restrict__ feat,
                                                     const float* __restrict__ We,
                                                     const float* __restrict__ nodeb,
                                                     float* __restrict__ agg) {
  int id = blockIdx.x * 256 + threadIdx.x;
  int e = id >> 5, o = id & 31;
  int src = ei[e];
  int dst = ei[NE + e];
  float fo = feat[src * H + o];
  const float* ear = ea + (size_t)e * ED;
  float ek[ED];
#pragma unroll
  for (int k = 0; k < ED; ++k) ek[k] = ear[k];
  float acc = nodeb[src * H + o];
#pragma unroll
  for (int i = 0; i < H; ++i) {
    float fi = __shfl(fo, i, 32);
    const float* wr = We + i * 512 + o * 16;
    float t = 0.f;
#pragma unroll
    for (int k = 0; k < ED; ++k) t = fmaf(ek[k], wr[k], t);
    acc = fmaf(fi, t, acc);
  }
  unsafeAtomicAdd(&agg[dst * H + o], acc);
}

// ---- fused GRU: gi = relu(agg)@Wih^T, gh = h@Whh^T (k_g-style), then gates ----
__global__ __launch_bounds__(256) void k_gru2(const float* __restrict__ agg,
                                              const float* __restrict__ Wih,
                                              const float* __restrict__ bih,
                                              const float* __restrict__ Whh,
                                              const float* __restrict__ bhh,
                                              float* __restrict__ feat) {
  __shared__ float wsw[6144];                  // XOR-swizzled [m][r][i^(r&31)]
  __shared__ float sm[GNPB * SMP];
  __shared__ float sh[GNPB * SMP];
  __shared__ float gil[GNPB * 96];
  __shared__ float ghl[GNPB * 96];
  int t = threadIdx.x;

  // stage weights (coalesced global read, swizzled LDS write) once per block
  for (int idx = t; idx < 3072; idx += 256) {
    int r = idx >> 5, i = idx & 31;
    int sw = (r << 5) | (i ^ (r & 31));
    wsw[sw]        = Wih[idx];
    wsw[3072 + sw] = Whh[idx];
  }
  __syncthreads();

  // register weight column: 48 tasks (24 ih + 24 hh) x 5 slots, t<240 active
  int task = t / 5;
  int slot = t - task * 5;
  bool act = task < 48;
  int c4 = (act ? (task < 24 ? task : task - 24) : 0) * 4;  // output base
  int mbase = (task < 24) ? 0 : 3072;
  float4 wcol[32];
  if (act) {
#pragma unroll
    for (int i = 0; i < 32; ++i) {
      wcol[i].x = wsw[mbase + ((c4 + 0) << 5) + (i ^ ((c4 + 0) & 31))];
      wcol[i].y = wsw[mbase + ((c4 + 1) << 5) + (i ^ ((c4 + 1) & 31))];
      wcol[i].z = wsw[mbase + ((c4 + 2) << 5) + (i ^ ((c4 + 2) & 31))];
      wcol[i].w = wsw[mbase + ((c4 + 3) << 5) + (i ^ ((c4 + 3) & 31))];
    }
  }

  for (int g0 = blockIdx.x; g0 < NN / GNPB; g0 += gridDim.x) {
    size_t base32 = (size_t)g0 * GNPB * 32;
    // stage m = relu(agg) and h = feat
    for (int idx = t; idx < GNPB * 32; idx += 256) {
      int ln = idx >> 5, i = idx & 31;
      sm[ln * SMP + i] = fmaxf(agg[base32 + idx], 0.f);
      sh[ln * SMP + i] = feat[base32 + idx];
    }
    __syncthreads();
    if (act) {
      const float* src = (task < 24) ? sm : sh;
      float* dstbuf = (task < 24) ? gil : ghl;
#pragma unroll
      for (int p = 0; p < 4; ++p) {
        int ln = 5 * p + slot;
        const float4* srow = (const float4*)(src + ln * SMP);
        float4 acc = {0.f, 0.f, 0.f, 0.f};
#pragma unroll
        for (int q = 0; q < 8; ++q) {
          float4 f = srow[q];
          float4 w0 = wcol[4 * q], w1 = wcol[4 * q + 1];
          float4 w2 = wcol[4 * q + 2], w3 = wcol[4 * q + 3];
          acc.x = fmaf(f.x, w0.x, acc.x); acc.y = fmaf(f.x, w0.y, acc.y);
          acc.z = fmaf(f.x, w0.z, acc.z); acc.w = fmaf(f.x, w0.w, acc.w);
          acc.x = fmaf(f.y, w1.x, acc.x); acc.y = fmaf(f.y, w1.y, acc.y);
          acc.z = fmaf(f.y, w1.z, acc.z); acc.w = fmaf(f.y, w1.w, acc.w);
          acc.x = fmaf(f.z, w2.x, acc.x); acc.y = fmaf(f.z, w2.y, acc.y);
          acc.z = fmaf(f.z, w2.z, acc.z); acc.w = fmaf(f.z, w2.w, acc.w);
          acc.x = fmaf(f.w, w3.x, acc.x); acc.y = fmaf(f.w, w3.y, acc.y);
          acc.z = fmaf(f.w, w3.z, acc.z); acc.w = fmaf(f.w, w3.w, acc.w);
        }
        *(float4*)(dstbuf + ln * 96 + c4) = acc;
      }
    }
    __syncthreads();
    // elementwise gates, write new h
    for (int idx = t; idx < GNPB * 32; idx += 256) {
      int ln = idx >> 5, o = idx & 31;
      float gir = gil[ln * 96 + o]       + bih[o];
      float giz = gil[ln * 96 + 32 + o]  + bih[32 + o];
      float gin = gil[ln * 96 + 64 + o]  + bih[64 + o];
      float ghr = ghl[ln * 96 + o]       + bhh[o];
      float ghz = ghl[ln * 96 + 32 + o]  + bhh[32 + o];
      float ghn = ghl[ln * 96 + 64 + o]  + bhh[64 + o];
      float h = sh[ln * SMP + o];
      float r = 1.f / (1.f + expf(-(gir + ghr)));
      float z = 1.f / (1.f + expf(-(giz + ghz)));
      float nn = tanhf(fmaf(r, ghn, gin));
      feat[base32 + idx] = (1.f - z) * nn + z * h;
    }
    __syncthreads();
  }
}

// ---- global mean pool ----
__global__ __launch_bounds__(256) void k_pool(const float* __restrict__ feat,
                                              const int* __restrict__ batch,
                                              float* __restrict__ pooled,
                                              float* __restrict__ cnts) {
  int id = blockIdx.x * 256 + threadIdx.x;     // N*32
  int n = id >> 5, o = id & 31;
  int b = batch[n];
  unsafeAtomicAdd(&pooled[b * H + o], feat[id]);
  if (o == 0) unsafeAtomicAdd(&cnts[b], 1.f);
}

// ---- final head ----
__global__ __launch_bounds__(256) void k_final(const float* __restrict__ pooled,
                                               const float* __restrict__ cnts,
                                               const float* __restrict__ W1,
                                               const float* __restrict__ b1,
                                               float* __restrict__ y) {
  int gph = blockIdx.x * 256 + threadIdx.x;
  if (gph >= NG) return;
  float c = fmaxf(cnts[gph], 1.f);
  float acc = 0.f;
#pragma unroll
  for (int o = 0; o < H; ++o) acc = fmaf(pooled[gph * H + o], W1[o], acc);
  y[gph] = acc / c + b1[0];
}

extern "C" void kernel_launch(void* const* d_in, const int* in_sizes, int n_in,
                              void* d_out, int out_size, void* d_ws, size_t ws_size,
                              hipStream_t stream) {
  const float* x     = (const float*)d_in[0];
  const int*   ei    = (const int*)d_in[1];
  const float* ea    = (const float*)d_in[2];
  const int*   batch = (const int*)d_in[3];
  const float* W0    = (const float*)d_in[4];
  const float* b0    = (const float*)d_in[5];
  const float* We    = (const float*)d_in[6];
  const float* be    = (const float*)d_in[7];
  const float* Wroot = (const float*)d_in[8];
  const float* bconv = (const float*)d_in[9];
  const float* Wih   = (const float*)d_in[10];
  const float* bih   = (const float*)d_in[11];
  const float* Whh   = (const float*)d_in[12];
  const float* bhh   = (const float*)d_in[13];
  const float* W1    = (const float*)d_in[14];
  const float* b1    = (const float*)d_in[15];

  float* ws     = (float*)d_ws;
  float* feat   = ws;                       // N*32
  float* agg    = ws + 3200000;             // N*32
  float* nodeb  = ws + 6400000;             // N*32
  float* pooled = ws + 9600000;             // G*32
  float* cnts   = ws + 9665536;             // G
  float* g      = ws + 9667584;             // N*512 (204.8 MB)
  const size_t need_g = (size_t)(9667584 + 51200000) * 4;
  bool use_g = ws_size >= need_g;

  const int NB_NODE = (NN * H) / 256;       // 12500, exact
  const int NB_EDGE = (NE * H) / 256;       // 50000, exact

  k_lin0<<<NB_NODE, 256, 0, stream>>>(x, W0, b0, feat);
  for (int it = 0; it < 3; ++it) {
    k_pre<<<NB_NODE, 256, 0, stream>>>(feat, Wroot, bconv, be, agg, nodeb);
    if (use_g) {
      k_g<<<NN / NPB, 256, 0, stream>>>(feat, We, g);
      k_edge<<<NB_EDGE, 256, 0, stream>>>(ei, ea, g, nodeb, agg);
    } else {
      k_edge_direct<<<NB_EDGE, 256, 0, stream>>>(ei, ea, feat, We, nodeb, agg);
    }
    k_gru2<<<768, 256, 0, stream>>>(agg, Wih, bih, Whh, bhh, feat);
  }
  hipMemsetAsync(pooled, 0, (size_t)(NG * H + NG) * 4, stream);
  k_pool<<<NB_NODE, 256, 0, stream>>>(feat, batch, pooled, cnts);
  k_final<<<(NG + 255) / 256, 256, 0, stream>>>(pooled, cnts, W1, b1, (float*)d_out);
}